// Round 1
// baseline (183.252 us; speedup 1.0000x reference)
//
#include <hip/hip_runtime.h>

#define NUM_REGIONS 116
#define EPS 1e-6f
#define GAMMA 1e-3f

// Fixed-point packing: low 40 bits = sum * 2^20, high 24 bits = count.
// Worst-case per-region total sum ~ 1.3e11 (~2^37) << 2^40; count ~108k << 2^24.
#define FIX_SCALE 1048576.0f
#define FIX_INV   (1.0f / 1048576.0f)
#define CNT_SHIFT 40
#define SUM_MASK  ((1ULL << CNT_SHIFT) - 1ULL)

typedef unsigned long long u64;

__global__ __launch_bounds__(256) void region_accum_kernel(
    const float* __restrict__ real,
    const float* __restrict__ fake,
    const int*   __restrict__ rmap,
    u64* __restrict__ g_acc,
    int n, int n4)
{
    // Per-wave privatized histograms: 4 waves x 116 bins of packed u64.
    __shared__ u64 s_acc[4][NUM_REGIONS];
    const int tid = threadIdx.x;
    u64* tbl = s_acc[tid >> 6];

    for (int i = tid; i < 4 * NUM_REGIONS; i += 256)
        (&s_acc[0][0])[i] = 0ULL;
    __syncthreads();

    const float4* real4 = (const float4*)real;
    const float4* fake4 = (const float4*)fake;
    const int4*   map4  = (const int4*)rmap;

    const int stride = gridDim.x * 256;
    for (int i = blockIdx.x * 256 + tid; i < n4; i += stride) {
        float4 a = real4[i];
        float4 b = fake4[i];
        int4   m = map4[i];
        u64 vx = (1ULL << CNT_SHIFT) | (u64)(unsigned)(fabsf(a.x - b.x) * FIX_SCALE + 0.5f);
        u64 vy = (1ULL << CNT_SHIFT) | (u64)(unsigned)(fabsf(a.y - b.y) * FIX_SCALE + 0.5f);
        u64 vz = (1ULL << CNT_SHIFT) | (u64)(unsigned)(fabsf(a.z - b.z) * FIX_SCALE + 0.5f);
        u64 vw = (1ULL << CNT_SHIFT) | (u64)(unsigned)(fabsf(a.w - b.w) * FIX_SCALE + 0.5f);
        atomicAdd(&tbl[m.x], vx);
        atomicAdd(&tbl[m.y], vy);
        atomicAdd(&tbl[m.z], vz);
        atomicAdd(&tbl[m.w], vw);
    }

    // Scalar tail (n not divisible by 4) — handled by block 0.
    const int tail_start = n4 << 2;
    if (blockIdx.x == 0 && tid < (n - tail_start)) {
        int idx = tail_start + tid;
        u64 v = (1ULL << CNT_SHIFT) |
                (u64)(unsigned)(fabsf(real[idx] - fake[idx]) * FIX_SCALE + 0.5f);
        atomicAdd(&tbl[rmap[idx]], v);
    }
    __syncthreads();

    // Merge 4 wave copies, one global u64 atomic per region per block.
    for (int r = tid; r < NUM_REGIONS; r += 256) {
        u64 t = s_acc[0][r] + s_acc[1][r] + s_acc[2][r] + s_acc[3][r];
        if (t) atomicAdd(&g_acc[r], t);
    }
}

__global__ __launch_bounds__(64) void region_finalize_kernel(
    const u64* __restrict__ g_acc,
    float* __restrict__ out,
    float inv_n)
{
    const int lane = threadIdx.x;  // 0..63, one wave
    // Region A = lane, region B = lane + 64 (only valid for lane < 52).
    u64 tA = g_acc[lane];
    float sA = (float)(tA & SUM_MASK) * FIX_INV;
    float cA = (float)(tA >> CNT_SHIFT);
    float mA = sA / (cA + EPS);

    float sB = 0.0f, mB = 0.0f;
    if (lane + 64 < NUM_REGIONS) {
        u64 tB = g_acc[lane + 64];
        sB = (float)(tB & SUM_MASK) * FIX_INV;
        float cB = (float)(tB >> CNT_SHIFT);
        mB = sB / (cB + EPS);
    }

    // max over regions (means are >= 0, absent slots contribute 0)
    float mx = fmaxf(mA, mB);
#pragma unroll
    for (int off = 32; off > 0; off >>= 1)
        mx = fmaxf(mx, __shfl_xor(mx, off));
    mx = fmaxf(mx, 0.0f);  // jnp.maximum(max, 0.0)

    const float k = GAMMA / (mx + EPS);
    // sum_r w_r * S_r, with w_r = 1 + GAMMA * mean_r / (max + EPS)
    float part = sA * (1.0f + mA * k) + sB * (1.0f + mB * k);
#pragma unroll
    for (int off = 32; off > 0; off >>= 1)
        part += __shfl_xor(part, off);

    if (lane == 0)
        out[0] = part * inv_n;
}

extern "C" void kernel_launch(void* const* d_in, const int* in_sizes, int n_in,
                              void* d_out, int out_size, void* d_ws, size_t ws_size,
                              hipStream_t stream) {
    const float* real = (const float*)d_in[0];
    const float* fake = (const float*)d_in[1];
    const int*   rmap = (const int*)d_in[2];
    float* out = (float*)d_out;

    const int n  = in_sizes[0];
    const int n4 = n >> 2;

    u64* g_acc = (u64*)d_ws;
    hipMemsetAsync(d_ws, 0, NUM_REGIONS * sizeof(u64), stream);

    int blocks = (n4 + 255) / 256;
    if (blocks > 2048) blocks = 2048;
    if (blocks < 1) blocks = 1;

    region_accum_kernel<<<blocks, 256, 0, stream>>>(real, fake, rmap, g_acc, n, n4);
    region_finalize_kernel<<<1, 64, 0, stream>>>(g_acc, out, 1.0f / (float)n);
}